// Round 1
// baseline (497.323 us; speedup 1.0000x reference)
//
#include <hip/hip_runtime.h>

// VectorQuantizer: x [32768, 256] fp32, codebook [1024, 256] fp32.
// Reference (recomputed by harness in float32):
//   d[n,k] = fl( fl( ||x_n||^2 - 2*dot(x_n,c_k) ) + ||c_k||^2 )   (all fp32)
//   idx = argmin_k (first min), out = codebook[idx]
// We REPLICATE the fp32 arithmetic exactly:
//  - dot: single sequential fp32 FMA chain over d ascending (v_fmac_f32, no
//    reassociation at -O3). The LDS staging round-trip is bit-exact (fp32 copy).
//  - q = (S - 2*acc) + cn in fp32: two roundings (2*acc exact), left-to-right.
//  - S/cnorm: fp64 butterfly sums rounded once to fp32 (unchanged chain).
//  - ties resolve to smallest k (strict <, ascending k traversal).
//
// R0->R1 structural change (stall elimination; compute-bound at 32% of the
// 157 TF fp32 roofline, stalled ~68%):
//  - x-tile staged ONCE into LDS (inner loop is pure LDS->reg->FMA; previously
//    x was re-read from global 16x with L2 latency exposed).
//  - T14 async-stage: next codebook chunk's global loads issued into REGISTERS
//    at chunk start (hidden under ~8192 cy of FMAs), ds_write after the
//    read-barrier. Only the LDS write drain + 2 barriers remain per chunk.
//  - distance-2 ping-pong (4 reg buffer sets) on the d-loop: every ds_read has
//    ~256 cy of slack. Needed because 141.5 KB LDS -> 1 block/CU (8 waves).
//  - cnorm prefetched to regs at chunk start.

#define D         256
#define K_TOTAL   1024
#define N_ROWS    32768
#define TM        64          // n-rows per block
#define TN        64          // k per chunk
#define NCHUNK    (K_TOTAL / TN)
#define CS_STRIDE 260         // 256 + 4 pad: rows 16B-aligned, b-reads 2-way bank (free)
#define NTHREADS  512
#define NI        2           // rows per thread  (n = ty + 32*i, ty in 0..31)
#define NJ        4           // ks   per thread  (k = tx + 16*j, tx in 0..15)

// ---------------- kernel 1: row norms for x and codebook ----------------
// 4 rows per wave (ILP across rows); per-row arithmetic chain and butterfly
// order are BIT-IDENTICAL to the previous version (fp32 squares -> fp64
// left-assoc sum of 4 -> shfl_down butterfly 32..1 -> single fp64->fp32 round).
__global__ void norms_kernel(const float* __restrict__ x, const float* __restrict__ cb,
                             float* __restrict__ xnorm, float* __restrict__ cnorm) {
    const int wave = threadIdx.x >> 6;          // 0..3
    const int lane = threadIdx.x & 63;
    const int row0 = (blockIdx.x * 4 + wave) * 4;   // 4 rows per wave

    double s[4];
    #pragma unroll
    for (int r = 0; r < 4; ++r) {
        const int row = row0 + r;
        const float* src = (row < N_ROWS) ? (x + (size_t)row * D)
                                          : (cb + (size_t)(row - N_ROWS) * D);
        float4 v = *(const float4*)(src + lane * 4);
        float sx = v.x * v.x;   // fp32 square (matches np elementwise fp32 mul)
        float sy = v.y * v.y;
        float sz = v.z * v.z;
        float sw = v.w * v.w;
        s[r] = (double)sx + (double)sy + (double)sz + (double)sw;
    }
    #pragma unroll
    for (int off = 32; off > 0; off >>= 1) {
        #pragma unroll
        for (int r = 0; r < 4; ++r) s[r] += __shfl_down(s[r], off, 64);
    }
    if (lane == 0) {
        #pragma unroll
        for (int r = 0; r < 4; ++r) {
            const int row = row0 + r;
            if (row < N_ROWS) xnorm[row] = (float)s[r];          // single rounding
            else              cnorm[row - N_ROWS] = (float)s[r];
        }
    }
}

// ---------------- kernel 2: fused fp32-replica distance + argmin + gather ----------------

// LDS loads for one d-group (4 d's): NI a-frags + NJ b-frags.
#define LOAD_G(aR, bR, ddv) do {                                               \
    _Pragma("unroll")                                                          \
    for (int i_ = 0; i_ < NI; ++i_)                                            \
        aR[i_] = *(const float4*)(xs + (ty + 32 * i_) * CS_STRIDE + (ddv));    \
    _Pragma("unroll")                                                          \
    for (int j_ = 0; j_ < NJ; ++j_)                                            \
        bR[j_] = *(const float4*)(cs + (tx + 16 * j_) * CS_STRIDE + (ddv));    \
} while (0)

// Sequential fp32 FMA chain per (i,j), d ascending — DO NOT reorder/split.
#define FMA_G(aR, bR) do {                                                     \
    _Pragma("unroll")                                                          \
    for (int i_ = 0; i_ < NI; ++i_) {                                          \
        _Pragma("unroll")                                                      \
        for (int j_ = 0; j_ < NJ; ++j_) {                                      \
            acc[i_][j_] += aR[i_].x * bR[j_].x;                                \
            acc[i_][j_] += aR[i_].y * bR[j_].y;                                \
            acc[i_][j_] += aR[i_].z * bR[j_].z;                                \
            acc[i_][j_] += aR[i_].w * bR[j_].w;                                \
        }                                                                      \
    }                                                                          \
} while (0)

__global__ __launch_bounds__(NTHREADS, 2)
void vq_kernel(const float* __restrict__ x, const float* __restrict__ cb,
               const float* __restrict__ xnorm, const float* __restrict__ cnorm,
               float* __restrict__ out) {
    __shared__ float xs[TM * CS_STRIDE];     // 66560 B x tile   [64 n][256 d]
    __shared__ float cs[TN * CS_STRIDE];     // 66560 B cb chunk [64 k][256 d]
    __shared__ float red_val[TM * 16];       // 4096 B
    __shared__ int   red_idx[TM * 16];       // 4096 B
    __shared__ int   best_idx[TM];           // 256 B   -> total 141568 B, 1 block/CU

    const int tid = threadIdx.x;
    const int tx  = tid & 15;                // k-group owner
    const int ty  = tid >> 4;                // n-group owner, 0..31
    const int n0  = blockIdx.x * TM;

    // staging geometry: 64 rows x 64 float4 = 4096 float4 / 512 thr = 8 each
    const int col4 = tid & 63;               // float4 column
    const int rowp = tid >> 6;               // 0..7

    // ---- prologue: stage x tile + cb chunk 0 (coalesced 16B) ----
    #pragma unroll
    for (int r = 0; r < 8; ++r) {
        const int rr = rowp + 8 * r;
        float4 v = *(const float4*)(x + (size_t)(n0 + rr) * D + col4 * 4);
        *(float4*)(xs + rr * CS_STRIDE + col4 * 4) = v;
    }
    #pragma unroll
    for (int r = 0; r < 8; ++r) {
        const int rr = rowp + 8 * r;
        float4 v = *(const float4*)(cb + (size_t)rr * D + col4 * 4);
        *(float4*)(cs + rr * CS_STRIDE + col4 * 4) = v;
    }

    float runmin[NI];
    int   runidx[NI];
    float S[NI];
    #pragma unroll
    for (int i = 0; i < NI; ++i) {
        runmin[i] = 1e30f; runidx[i] = 0;
        S[i] = xnorm[n0 + ty + 32 * i];
    }
    __syncthreads();

    for (int kc = 0; kc < NCHUNK; ++kc) {
        const int k0 = kc * TN;

        // T14: issue next chunk's cb loads into regs NOW; they complete under
        // the ~8192-cycle FMA loop. ds_write happens after the read-barrier.
        float4 sreg[8];
        if (kc + 1 < NCHUNK) {
            const int kn = k0 + TN;
            #pragma unroll
            for (int r = 0; r < 8; ++r) {
                const int rr = rowp + 8 * r;
                sreg[r] = *(const float4*)(cb + (size_t)(kn + rr) * D + col4 * 4);
            }
        }
        // prefetch this chunk's cnorms (consumed ~8192 cy later in epilogue)
        float cn[NJ];
        #pragma unroll
        for (int j = 0; j < NJ; ++j) cn[j] = cnorm[k0 + tx + 16 * j];

        float acc[NI][NJ];
        #pragma unroll
        for (int i = 0; i < NI; ++i)
            #pragma unroll
            for (int j = 0; j < NJ; ++j) acc[i][j] = 0.f;

        // ---- d-loop: distance-2 software pipeline, 4 buffer sets ----
        // 64 groups of 4 d's; group g's ds_reads issue while computing g-2.
        float4 aA[NI], bA[NJ], aB[NI], bB[NJ], aC[NI], bC[NJ], aD[NI], bD[NJ];
        LOAD_G(aA, bA, 0);
        LOAD_G(aB, bB, 4);
        #pragma unroll 1
        for (int it = 0; it < 15; ++it) {
            const int base = it * 16;
            LOAD_G(aC, bC, base + 8);
            FMA_G(aA, bA);                   // group base+0
            LOAD_G(aD, bD, base + 12);
            FMA_G(aB, bB);                   // group base+4
            LOAD_G(aA, bA, base + 16);
            FMA_G(aC, bC);                   // group base+8
            LOAD_G(aB, bB, base + 20);
            FMA_G(aD, bD);                   // group base+12
        }
        LOAD_G(aC, bC, 248);
        FMA_G(aA, bA);                       // 240
        LOAD_G(aD, bD, 252);
        FMA_G(aB, bB);                       // 244
        FMA_G(aC, bC);                       // 248
        FMA_G(aD, bD);                       // 252

        // np-replica fp32 distance: q = (S - 2*acc) + cn, two fp32 roundings.
        // Ascending j/kc == ascending k; strict < keeps first index on ties.
        #pragma unroll
        for (int j = 0; j < NJ; ++j) {
            const int k = k0 + tx + 16 * j;
            #pragma unroll
            for (int i = 0; i < NI; ++i) {
                const float t = S[i] - 2.0f * acc[i][j];   // one rounding (2*acc exact)
                const float q = t + cn[j];                 // second rounding
                if (q < runmin[i]) { runmin[i] = q; runidx[i] = k; }
            }
        }

        __syncthreads();                     // all waves done READING cs
        if (kc + 1 < NCHUNK) {
            #pragma unroll
            for (int r = 0; r < 8; ++r) {    // ~512 cy LDS drain, only exposed cost
                const int rr = rowp + 8 * r;
                *(float4*)(cs + rr * CS_STRIDE + col4 * 4) = sreg[r];
            }
            __syncthreads();                 // cs ready for chunk kc+1
        }
    }

    // cross-thread argmin merge per n-row (16 tx candidates), index tie-break
    #pragma unroll
    for (int i = 0; i < NI; ++i) {
        const int row = ty + 32 * i;
        red_val[row * 16 + tx] = runmin[i];
        red_idx[row * 16 + tx] = runidx[i];
    }
    __syncthreads();
    if (tid < TM) {
        const int row = tid;
        float bv = red_val[row * 16];
        int   bi = red_idx[row * 16];
        #pragma unroll
        for (int t = 1; t < 16; ++t) {
            const float v = red_val[row * 16 + t];
            const int  ix = red_idx[row * 16 + t];
            if (v < bv || (v == bv && ix < bi)) { bv = v; bi = ix; }
        }
        best_idx[row] = bi;
    }
    __syncthreads();

    {   // gather winning codebook rows -> out, coalesced 16B
        #pragma unroll
        for (int r = 0; r < 8; ++r) {
            const int rr = rowp + 8 * r;
            const int k  = best_idx[rr];
            float4 v = *(const float4*)(cb + (size_t)k * D + col4 * 4);
            *(float4*)(out + (size_t)(n0 + rr) * D + col4 * 4) = v;
        }
    }
}

extern "C" void kernel_launch(void* const* d_in, const int* in_sizes, int n_in,
                              void* d_out, int out_size, void* d_ws, size_t ws_size,
                              hipStream_t stream) {
    const float* x  = (const float*)d_in[0];   // [32768, 256]
    const float* cb = (const float*)d_in[1];   // [1024, 256]
    float* out = (float*)d_out;                // [32768, 256]

    // workspace: xnorm [32768 fp32] | cnorm [1024 fp32]  (132 KB)
    float* xnorm = (float*)d_ws;
    float* cnorm = xnorm + N_ROWS;

    norms_kernel<<<(N_ROWS + K_TOTAL) / 16, 256, 0, stream>>>(x, cb, xnorm, cnorm);
    vq_kernel<<<N_ROWS / TM, NTHREADS, 0, stream>>>(x, cb, xnorm, cnorm, out);
}

// Round 2
// 479.763 us; speedup vs baseline: 1.0366x; 1.0366x over previous
//
#include <hip/hip_runtime.h>

// VectorQuantizer: x [32768, 256] fp32, codebook [1024, 256] fp32.
// Reference (recomputed by harness in float32):
//   d[n,k] = fl( fl( ||x_n||^2 - 2*dot(x_n,c_k) ) + ||c_k||^2 )   (all fp32)
//   idx = argmin_k (first min), out = codebook[idx]
// We REPLICATE the fp32 arithmetic exactly:
//  - dot: single sequential fp32 FMA chain over d ascending (v_fmac_f32, no
//    reassociation at -O3). The LDS staging round-trip is bit-exact (fp32 copy).
//  - q = (S - 2*acc) + cn in fp32: two roundings (2*acc exact), left-to-right.
//  - S/cnorm: fp64 butterfly sums rounded once to fp32 (unchanged chain).
//  - ties resolve to smallest k (strict <, ascending k traversal).
//
// R1 post-mortem: x-in-LDS halved FETCH_SIZE (correct theory) but the manual
// distance-2 pipeline (4 reg buffer sets, ~96 VGPR) blew the live set ->
// compiler spilled to scratch (WRITE_SIZE 33->275 MB, ~240 MB spill traffic)
// -> 488 us. R2 keeps the structure, DELETES the manual pipeline (compiler
// schedules ds_read->FMA near-optimally on its own), keeps T14 reg-prefetch
// of the next codebook chunk. Live set ~110 VGPR -> no spill.

#define D         256
#define K_TOTAL   1024
#define N_ROWS    32768
#define TM        64          // n-rows per block
#define TN        64          // k per chunk
#define NCHUNK    (K_TOTAL / TN)
#define CS_STRIDE 260         // 256 + 4 pad: rows 16B-aligned, b-reads 2-way bank (free)
#define NTHREADS  512
#define NI        2           // rows per thread  (n = ty + 32*i, ty in 0..31)
#define NJ        4           // ks   per thread  (k = tx + 16*j, tx in 0..15)

// ---------------- kernel 1: row norms for x and codebook ----------------
// 4 rows per wave (ILP across rows); per-row arithmetic chain and butterfly
// order are BIT-IDENTICAL to R0 (fp32 squares -> fp64 left-assoc sum of 4 ->
// shfl_down butterfly 32..1 -> single fp64->fp32 round).
__global__ void norms_kernel(const float* __restrict__ x, const float* __restrict__ cb,
                             float* __restrict__ xnorm, float* __restrict__ cnorm) {
    const int wave = threadIdx.x >> 6;          // 0..3
    const int lane = threadIdx.x & 63;
    const int row0 = (blockIdx.x * 4 + wave) * 4;   // 4 rows per wave

    double s[4];
    #pragma unroll
    for (int r = 0; r < 4; ++r) {
        const int row = row0 + r;
        const float* src = (row < N_ROWS) ? (x + (size_t)row * D)
                                          : (cb + (size_t)(row - N_ROWS) * D);
        float4 v = *(const float4*)(src + lane * 4);
        float sx = v.x * v.x;   // fp32 square (matches np elementwise fp32 mul)
        float sy = v.y * v.y;
        float sz = v.z * v.z;
        float sw = v.w * v.w;
        s[r] = (double)sx + (double)sy + (double)sz + (double)sw;
    }
    #pragma unroll
    for (int off = 32; off > 0; off >>= 1) {
        #pragma unroll
        for (int r = 0; r < 4; ++r) s[r] += __shfl_down(s[r], off, 64);
    }
    if (lane == 0) {
        #pragma unroll
        for (int r = 0; r < 4; ++r) {
            const int row = row0 + r;
            if (row < N_ROWS) xnorm[row] = (float)s[r];          // single rounding
            else              cnorm[row - N_ROWS] = (float)s[r];
        }
    }
}

// ---------------- kernel 2: fused fp32-replica distance + argmin + gather ----------------
__global__ __launch_bounds__(NTHREADS, 2)
void vq_kernel(const float* __restrict__ x, const float* __restrict__ cb,
               const float* __restrict__ xnorm, const float* __restrict__ cnorm,
               float* __restrict__ out) {
    __shared__ float xs[TM * CS_STRIDE];     // 66560 B x tile   [64 n][256 d]
    __shared__ float cs[TN * CS_STRIDE];     // 66560 B cb chunk [64 k][256 d]
    __shared__ float red_val[TM * 16];       // 4096 B
    __shared__ int   red_idx[TM * 16];       // 4096 B
    __shared__ int   best_idx[TM];           // 256 B   -> total 141568 B, 1 block/CU

    const int tid = threadIdx.x;
    const int tx  = tid & 15;                // k-group owner
    const int ty  = tid >> 4;                // n-group owner, 0..31
    const int n0  = blockIdx.x * TM;

    // staging geometry: 64 rows x 64 float4 = 4096 float4 / 512 thr = 8 each
    const int col4 = tid & 63;               // float4 column
    const int rowp = tid >> 6;               // 0..7

    // ---- prologue: stage x tile + cb chunk 0 (coalesced 16B) ----
    #pragma unroll
    for (int r = 0; r < 8; ++r) {
        const int rr = rowp + 8 * r;
        float4 v = *(const float4*)(x + (size_t)(n0 + rr) * D + col4 * 4);
        *(float4*)(xs + rr * CS_STRIDE + col4 * 4) = v;
    }
    #pragma unroll
    for (int r = 0; r < 8; ++r) {
        const int rr = rowp + 8 * r;
        float4 v = *(const float4*)(cb + (size_t)rr * D + col4 * 4);
        *(float4*)(cs + rr * CS_STRIDE + col4 * 4) = v;
    }

    float runmin[NI];
    int   runidx[NI];
    float S[NI];
    #pragma unroll
    for (int i = 0; i < NI; ++i) {
        runmin[i] = 1e30f; runidx[i] = 0;
        S[i] = xnorm[n0 + ty + 32 * i];
    }
    __syncthreads();

    for (int kc = 0; kc < NCHUNK; ++kc) {
        const int k0 = kc * TN;

        // T14: issue next chunk's cb loads into regs NOW; they complete under
        // the ~8192-cycle FMA loop. ds_write happens after the read-barrier.
        float4 sreg[8];
        if (kc + 1 < NCHUNK) {
            const int kn = k0 + TN;
            #pragma unroll
            for (int r = 0; r < 8; ++r) {
                const int rr = rowp + 8 * r;
                sreg[r] = *(const float4*)(cb + (size_t)(kn + rr) * D + col4 * 4);
            }
        }
        // prefetch this chunk's cnorms (consumed ~8192 cy later in epilogue)
        float cn[NJ];
        #pragma unroll
        for (int j = 0; j < NJ; ++j) cn[j] = cnorm[k0 + tx + 16 * j];

        float acc[NI][NJ];
        #pragma unroll
        for (int i = 0; i < NI; ++i)
            #pragma unroll
            for (int j = 0; j < NJ; ++j) acc[i][j] = 0.f;

        // ---- d-loop: ONE transient a/b set, compiler-scheduled. ----
        // Sequential fp32 FMA chain per (i,j), d ascending — DO NOT reorder.
        #pragma unroll 4
        for (int dd = 0; dd < D; dd += 4) {
            float4 a[NI], b[NJ];
            #pragma unroll
            for (int i = 0; i < NI; ++i)
                a[i] = *(const float4*)(xs + (ty + 32 * i) * CS_STRIDE + dd);
            #pragma unroll
            for (int j = 0; j < NJ; ++j)
                b[j] = *(const float4*)(cs + (tx + 16 * j) * CS_STRIDE + dd);
            #pragma unroll
            for (int i = 0; i < NI; ++i)
                #pragma unroll
                for (int j = 0; j < NJ; ++j) {
                    acc[i][j] += a[i].x * b[j].x;
                    acc[i][j] += a[i].y * b[j].y;
                    acc[i][j] += a[i].z * b[j].z;
                    acc[i][j] += a[i].w * b[j].w;
                }
        }

        // np-replica fp32 distance: q = (S - 2*acc) + cn, two fp32 roundings.
        // Ascending j/kc == ascending k; strict < keeps first index on ties.
        #pragma unroll
        for (int j = 0; j < NJ; ++j) {
            const int k = k0 + tx + 16 * j;
            #pragma unroll
            for (int i = 0; i < NI; ++i) {
                const float t = S[i] - 2.0f * acc[i][j];   // one rounding (2*acc exact)
                const float q = t + cn[j];                 // second rounding
                if (q < runmin[i]) { runmin[i] = q; runidx[i] = k; }
            }
        }

        __syncthreads();                     // all waves done READING cs
        if (kc + 1 < NCHUNK) {
            #pragma unroll
            for (int r = 0; r < 8; ++r) {    // LDS drain, only exposed staging cost
                const int rr = rowp + 8 * r;
                *(float4*)(cs + rr * CS_STRIDE + col4 * 4) = sreg[r];
            }
            __syncthreads();                 // cs ready for chunk kc+1
        }
    }

    // cross-thread argmin merge per n-row (16 tx candidates), index tie-break
    #pragma unroll
    for (int i = 0; i < NI; ++i) {
        const int row = ty + 32 * i;
        red_val[row * 16 + tx] = runmin[i];
        red_idx[row * 16 + tx] = runidx[i];
    }
    __syncthreads();
    if (tid < TM) {
        const int row = tid;
        float bv = red_val[row * 16];
        int   bi = red_idx[row * 16];
        #pragma unroll
        for (int t = 1; t < 16; ++t) {
            const float v = red_val[row * 16 + t];
            const int  ix = red_idx[row * 16 + t];
            if (v < bv || (v == bv && ix < bi)) { bv = v; bi = ix; }
        }
        best_idx[row] = bi;
    }
    __syncthreads();

    {   // gather winning codebook rows -> out, coalesced 16B
        #pragma unroll
        for (int r = 0; r < 8; ++r) {
            const int rr = rowp + 8 * r;
            const int k  = best_idx[rr];
            float4 v = *(const float4*)(cb + (size_t)k * D + col4 * 4);
            *(float4*)(out + (size_t)(n0 + rr) * D + col4 * 4) = v;
        }
    }
}

extern "C" void kernel_launch(void* const* d_in, const int* in_sizes, int n_in,
                              void* d_out, int out_size, void* d_ws, size_t ws_size,
                              hipStream_t stream) {
    const float* x  = (const float*)d_in[0];   // [32768, 256]
    const float* cb = (const float*)d_in[1];   // [1024, 256]
    float* out = (float*)d_out;                // [32768, 256]

    // workspace: xnorm [32768 fp32] | cnorm [1024 fp32]  (132 KB)
    float* xnorm = (float*)d_ws;
    float* cnorm = xnorm + N_ROWS;

    norms_kernel<<<(N_ROWS + K_TOTAL) / 16, 256, 0, stream>>>(x, cb, xnorm, cnorm);
    vq_kernel<<<N_ROWS / TM, NTHREADS, 0, stream>>>(x, cb, xnorm, cnorm, out);
}